// Round 8
// baseline (889.324 us; speedup 1.0000x reference)
//
#include <hip/hip_runtime.h>

// Attention_11845519803093 — R14: one wave per block (max TLP, zero coupling).
//   * attn grid 7104 x 64thr: 192 heads x 37 q-tiles of 16 rows, ONE wave each.
//     All LDS intra-wave -> no barriers at all; residency up to 16 blocks/CU
//     (LDS 4.6KB; __launch_bounds__(64,4) -> 128-VGPR budget, same as R11 best).
//   * Loop body = R11 verbatim (batched 24 frag loads, per-element bias gather),
//     exp2 path (Q prescaled 0.125*log2e in qkv_gemm).
//   * TvS LDS staging dropped; epilogue reads tvv/tvh direct from global (L2-hot).
// ws layout: qh | kh | vh (fp16) | ao (fp32) | M2

#define BB    16
#define NNq   577
#define DIMM  768
#define NHh   12
#define HD    64
#define MM    9232
#define KT    64
#define NPAD  640

typedef _Float16 h8 __attribute__((ext_vector_type(8)));
typedef float    f4 __attribute__((ext_vector_type(4)));

__device__ inline h8 pack8(float4 a, float4 b) {
    h8 r;
    r[0]=(_Float16)a.x; r[1]=(_Float16)a.y; r[2]=(_Float16)a.z; r[3]=(_Float16)a.w;
    r[4]=(_Float16)b.x; r[5]=(_Float16)b.y; r[6]=(_Float16)b.z; r[7]=(_Float16)b.w;
    return r;
}

// ---------------------------------------------------------------- mask table + V pad fill
__global__ void mask_init(_Float16* __restrict__ M2g, _Float16* __restrict__ vh)
{
    const int id = blockIdx.x*256 + threadIdx.x;
    if (id < NPAD*64) {
        const int key = id >> 6, bin = id & 63;
        int vb = 255, hb = 255;
        if (key == 0)      { vb = 24; hb = 49; }
        else if (key < NNq){ const int kq = key-1, kv = kq/24; vb = kv; hb = 25 + (kq - kv*24); }
        M2g[bin*NPAD + key] =
            ((key < NNq) && (bin==vb || bin==hb || bin==50)) ? (_Float16)1.f : (_Float16)0.f;
    }
    const int vid = id - NPAD*64;
    if (vid >= 0 && vid < BB*NHh*HD*64) {
        const int head = vid >> 12;
        const int rem  = vid & 4095;
        const int d    = rem >> 6;
        const int col  = 576 + (rem & 63);
        vh[(size_t)head*(HD*NPAD) + (size_t)d*NPAD + col] = (_Float16)0.f;
    }
}

// ---------------------------------------------------------------- split-fp16 MFMA GEMM core
template <typename F>
__device__ __forceinline__ void gemm128(const float* __restrict__ Amat,
                                        const float* __restrict__ Bmat,
                                        F epi)
{
    __shared__ _Float16 Ah[128][40], Al[128][40], Bh[128][40], Bl[128][40];
    const int t  = threadIdx.x;
    const int wv = t >> 6, lane = t & 63, lo = lane & 15, g = lane >> 4;
    const int wm = (wv >> 1) << 6, wn = (wv & 1) << 6;
    const int bm = blockIdx.y << 7, bn = blockIdx.x << 7;
    f4 acc[4][4] = {};
    const int lr = t >> 1;
    const int lc = (t & 1) << 4;
    const int am = bm + lr;
    const bool aok = am < MM;
    const float* arow = Amat + (size_t)(aok ? am : 0) * DIMM + lc;
    const float* brow = Bmat + (size_t)(bn + lr) * DIMM + lc;

    for (int k0 = 0; k0 < DIMM; k0 += 32) {
        float4 a0 = make_float4(0,0,0,0), a1 = a0, a2 = a0, a3 = a0;
        if (aok) {
            a0 = *(const float4*)(arow + k0);      a1 = *(const float4*)(arow + k0 + 4);
            a2 = *(const float4*)(arow + k0 + 8);  a3 = *(const float4*)(arow + k0 + 12);
        }
        const float4 b0 = *(const float4*)(brow + k0);
        const float4 b1 = *(const float4*)(brow + k0 + 4);
        const float4 b2 = *(const float4*)(brow + k0 + 8);
        const float4 b3 = *(const float4*)(brow + k0 + 12);
        __syncthreads();
        {
            const h8 ah0 = pack8(a0, a1), ah1 = pack8(a2, a3);
            float4 r0, r1, r2, r3;
            r0.x=a0.x-(float)ah0[0]; r0.y=a0.y-(float)ah0[1]; r0.z=a0.z-(float)ah0[2]; r0.w=a0.w-(float)ah0[3];
            r1.x=a1.x-(float)ah0[4]; r1.y=a1.y-(float)ah0[5]; r1.z=a1.z-(float)ah0[6]; r1.w=a1.w-(float)ah0[7];
            r2.x=a2.x-(float)ah1[0]; r2.y=a2.y-(float)ah1[1]; r2.z=a2.z-(float)ah1[2]; r2.w=a2.w-(float)ah1[3];
            r3.x=a3.x-(float)ah1[4]; r3.y=a3.y-(float)ah1[5]; r3.z=a3.z-(float)ah1[6]; r3.w=a3.w-(float)ah1[7];
            *(h8*)&Ah[lr][lc]   = ah0;  *(h8*)&Ah[lr][lc+8] = ah1;
            *(h8*)&Al[lr][lc]   = pack8(r0, r1);
            *(h8*)&Al[lr][lc+8] = pack8(r2, r3);
        }
        {
            const h8 bh0 = pack8(b0, b1), bh1 = pack8(b2, b3);
            float4 r0, r1, r2, r3;
            r0.x=b0.x-(float)bh0[0]; r0.y=b0.y-(float)bh0[1]; r0.z=b0.z-(float)bh0[2]; r0.w=b0.w-(float)bh0[3];
            r1.x=b1.x-(float)bh0[4]; r1.y=b1.y-(float)bh0[5]; r1.z=b1.z-(float)bh0[6]; r1.w=b1.w-(float)bh0[7];
            r2.x=b2.x-(float)bh1[0]; r2.y=b2.y-(float)bh1[1]; r2.z=b2.z-(float)bh1[2]; r2.w=b2.w-(float)bh1[3];
            r3.x=b3.x-(float)bh1[4]; r3.y=b3.y-(float)bh1[5]; r3.z=b3.z-(float)bh1[6]; r3.w=b3.w-(float)bh1[7];
            *(h8*)&Bh[lr][lc]   = bh0;  *(h8*)&Bh[lr][lc+8] = bh1;
            *(h8*)&Bl[lr][lc]   = pack8(r0, r1);
            *(h8*)&Bl[lr][lc+8] = pack8(r2, r3);
        }
        __syncthreads();
        h8 fah[4], fal[4], fbh[4], fbl[4];
        #pragma unroll
        for (int i = 0; i < 4; ++i) {
            fah[i] = *(const h8*)&Ah[wm + 16*i + lo][g<<3];
            fal[i] = *(const h8*)&Al[wm + 16*i + lo][g<<3];
            fbh[i] = *(const h8*)&Bh[wn + 16*i + lo][g<<3];
            fbl[i] = *(const h8*)&Bl[wn + 16*i + lo][g<<3];
        }
        #pragma unroll
        for (int mi = 0; mi < 4; ++mi) {
            #pragma unroll
            for (int ni = 0; ni < 4; ++ni) {
                acc[mi][ni] = __builtin_amdgcn_mfma_f32_16x16x32_f16(fah[mi], fbh[ni], acc[mi][ni], 0, 0, 0);
                acc[mi][ni] = __builtin_amdgcn_mfma_f32_16x16x32_f16(fah[mi], fbl[ni], acc[mi][ni], 0, 0, 0);
                acc[mi][ni] = __builtin_amdgcn_mfma_f32_16x16x32_f16(fal[mi], fbh[ni], acc[mi][ni], 0, 0, 0);
            }
        }
    }
    epi(acc, bm, bn, wm, wn, lo, g);
}

// ---------------------------------------------------------------- QKV GEMM (MFMA)
__global__ __launch_bounds__(256, 2)
void qkv_gemm(const float* __restrict__ x, const float* __restrict__ w,
              _Float16* __restrict__ qh, _Float16* __restrict__ kh, _Float16* __restrict__ vh)
{
    gemm128(x, w, [=](f4 (&acc)[4][4], int bm, int bn, int wm, int wn, int lo, int g) {
        const int three = bn / 768;
        const int cb    = bn - three * 768;
        #pragma unroll
        for (int mi = 0; mi < 4; ++mi) {
            #pragma unroll
            for (int reg = 0; reg < 4; ++reg) {
                const int m = bm + wm + 16*mi + 4*g + reg;
                if (m >= MM) continue;
                const int b_ = m / NNq;
                const int n_ = m - b_ * NNq;
                #pragma unroll
                for (int ni = 0; ni < 4; ++ni) {
                    const int n  = cb + wn + 16*ni + lo;
                    const int hh = n >> 6;
                    const int d  = n & 63;
                    if (three == 0) {
                        // Q fp16 [head][640][64], scaled by 0.125*log2(e) for exp2 path
                        qh[((size_t)(b_*NHh + hh)*NPAD + n_)*HD + d] =
                            (_Float16)(acc[mi][ni][reg] * 0.18033688f);
                    } else if (three == 1) {
                        kh[((size_t)(b_*NHh + hh)*NPAD + n_)*HD + d] = (_Float16)acc[mi][ni][reg];
                    } else {
                        vh[((size_t)(b_*NHh + hh)*HD + d)*NPAD + n_] = (_Float16)acc[mi][ni][reg];
                    }
                }
            }
        }
    });
}

// ---------------------------------------------------------------- proj GEMM (MFMA)
__global__ __launch_bounds__(256, 2)
void proj_gemm(const float* __restrict__ A, const float* __restrict__ w,
               const float* __restrict__ bias, float* __restrict__ out)
{
    gemm128(A, w, [=](f4 (&acc)[4][4], int bm, int bn, int wm, int wn, int lo, int g) {
        #pragma unroll
        for (int ni = 0; ni < 4; ++ni) {
            const int n  = bn + wn + 16*ni + lo;
            const float bb = bias[n];
            #pragma unroll
            for (int mi = 0; mi < 4; ++mi) {
                #pragma unroll
                for (int reg = 0; reg < 4; ++reg) {
                    const int m = bm + wm + 16*mi + 4*g + reg;
                    if (m >= MM) continue;
                    out[(size_t)m*DIMM + n] = acc[mi][ni][reg] + bb;
                }
            }
        }
    });
}

// ---------------------------------------------------------------- fused attention v12 (1 wave / block)
__global__ __launch_bounds__(64, 4)
void attn_fused(const _Float16* __restrict__ qh,
                const _Float16* __restrict__ kh, const _Float16* __restrict__ vh,
                const float* __restrict__ tkv, const float* __restrict__ tkh,
                const float* __restrict__ tvv, const float* __restrict__ tvh,
                const _Float16* __restrict__ M2g,
                float* __restrict__ ao)
{
    // LDS 4608 B (all intra-wave, NO barriers anywhere):
    //   [   0,2304) qrelS fp16 [16][72]
    //   [2304,4608) Pt    fp16 [16][72]
    //   epilogue: binsS fp32 [16][52] at 0 (3328 B; qrelS + head of Pt, both dead)
    __shared__ __align__(16) char smem[4608];
    _Float16 (*qrelS)[72] = (_Float16(*)[72])(smem);
    _Float16 (*Pt)[72]    = (_Float16(*)[72])(smem + 2304);
    float    (*binsS)[52] = (float(*)[52])(smem);

    const int lane = threadIdx.x & 63;
    const int lo   = lane & 15;
    const int g    = lane >> 4;
    const int gb   = g << 3;

    // ---- XCD-chunked decode: head % 8 == block % 8 ----
    const int blk = blockIdx.x;        // 0..7103
    const int x8  = blk & 7;
    const int r_  = blk >> 3;          // 0..887
    const int hq  = r_ / 37;           // 0..23
    const int qt  = r_ - hq*37;        // 0..36
    const int bh  = x8 + (hq << 3);    // head 0..191
    const int qt0 = qt * 16;
    const int qrow = 4*g;              // rows 0..15 within tile
    const _Float16* qp = qh + (size_t)bh * (NPAD*HD);
    const _Float16* kp = kh + (size_t)bh * (NPAD*HD);
    const _Float16* vp = vh + (size_t)bh * (HD*NPAD);

    // ---- Q fragments straight from global (qh fp16 [640][64], log2-prescaled) ----
    const h8 a0 = *(const h8*)(qp + (size_t)(qt0 + lo)*HD + gb);
    const h8 a1 = *(const h8*)(qp + (size_t)(qt0 + lo)*HD + 32 + gb);

    // ---- qrel = Q @ T^T via MFMA (16 q x 60 r x 64 d) ----
    {
        f4 qacc[4] = {f4{0,0,0,0}, f4{0,0,0,0}, f4{0,0,0,0}, f4{0,0,0,0}};
        #pragma unroll
        for (int c = 0; c < 4; ++c) {
            const int r16 = 16*c + lo;
            const float* src = (r16 < 30) ? (tkv + r16*HD) : (tkh + (r16-30)*HD);
            h8 tb0 = {}, tb1 = {};
            if (r16 < 60) {
                tb0 = pack8(*(const float4*)(src + gb),      *(const float4*)(src + gb + 4));
                tb1 = pack8(*(const float4*)(src + 32 + gb), *(const float4*)(src + 32 + gb + 4));
            }
            qacc[c] = __builtin_amdgcn_mfma_f32_16x16x32_f16(a0, tb0, qacc[c], 0, 0, 0);
            qacc[c] = __builtin_amdgcn_mfma_f32_16x16x32_f16(a1, tb1, qacc[c], 0, 0, 0);
        }
        #pragma unroll
        for (int c = 0; c < 4; ++c) {
            #pragma unroll
            for (int i = 0; i < 4; ++i)
                qrelS[qrow + i][16*c + lo] = (_Float16)qacc[c][i];
        }
    }

    int qv_[4], qh_[4];
    bool q0_[4];
    #pragma unroll
    for (int i = 0; i < 4; ++i) {
        const int qgl = qt0 + qrow + i;
        q0_[i] = (qgl == 0);
        int qq = qgl - 1; if (qq < 0) qq = 0;
        qv_[i] = qq / 24;
        qh_[i] = qq - qv_[i]*24;
    }

    f4 o_acc [4] = {f4{0,0,0,0}, f4{0,0,0,0}, f4{0,0,0,0}, f4{0,0,0,0}};
    f4 binacc[4] = {f4{0,0,0,0}, f4{0,0,0,0}, f4{0,0,0,0}, f4{0,0,0,0}};

    // per-lane base pointers
    const _Float16* kptr = kp + (size_t)lo*HD + gb;
    const _Float16* vptr = vp + (size_t)lo*NPAD + gb;
    const _Float16* m2p  = M2g + (size_t)lo*NPAD + gb;

    // ================= barrier-free K loop (10 tiles) =================
    for (int kt0 = 0; kt0 < NNq; kt0 += KT) {
        // ---- batch-issue ALL global fragment loads for this tile ----
        h8 kb0[4], kb1[4], v0r[4], v1r[4], m20[4], m21[4];
        #pragma unroll
        for (int c = 0; c < 4; ++c) {
            kb0[c] = *(const h8*)(kptr + c*(16*HD));
            kb1[c] = *(const h8*)(kptr + c*(16*HD) + 32);
            v0r[c] = *(const h8*)(vptr + c*(16*NPAD));
            v1r[c] = *(const h8*)(vptr + c*(16*NPAD) + 32);
            m20[c] = *(const h8*)(m2p  + c*(16*NPAD));
            m21[c] = *(const h8*)(m2p  + c*(16*NPAD) + 32);
        }
        kptr += KT*HD; vptr += KT; m2p += KT;
        // ---- S = Q·K^T (MFMA, log2 units) ----
        f4 Sc[4];
        #pragma unroll
        for (int c = 0; c < 4; ++c) {
            f4 acc = f4{0,0,0,0};
            acc = __builtin_amdgcn_mfma_f32_16x16x32_f16(a0, kb0[c], acc, 0, 0, 0);
            acc = __builtin_amdgcn_mfma_f32_16x16x32_f16(a1, kb1[c], acc, 0, 0, 0);
            Sc[c] = acc;
        }
        // ---- S += rel (2-hot gather from qrelS), P = exp2(S) ----
        #pragma unroll
        for (int c = 0; c < 4; ++c) {
            const int key = kt0 + 16*c + lo;
            const bool ok = key < NNq;
            int kk = key - 1; if (kk < 0) kk = 0;
            const int kv  = kk / 24;
            const int kh2 = kk - kv*24;
            const bool kz = (key == 0);
            #pragma unroll
            for (int i = 0; i < 4; ++i) {
                int colv, colh;
                if (kz || q0_[i]) { colv = 0; colh = 30; }
                else {
                    int dv = kv  - qv_[i]; dv = min(14, max(-14, dv));
                    int dh = kh2 - qh_[i]; dh = min(14, max(-14, dh));
                    colv = dv + 15;
                    colh = 45 + dh;
                }
                const float srel = (float)qrelS[qrow+i][colv] + (float)qrelS[qrow+i][colh];
                const float p = ok ? exp2f(Sc[c][i] + srel) : 0.f;
                Pt[qrow+i][16*c + lo] = (_Float16)p;
            }
        }
        // ---- P fragments (same wave; lgkmcnt ordering only) ----
        const h8 p0 = *(const h8*)&Pt[lo][gb];
        const h8 p1 = *(const h8*)&Pt[lo][32 + gb];
        // ---- bins += P @ M2^T ----
        #pragma unroll
        for (int c = 0; c < 4; ++c) {
            binacc[c] = __builtin_amdgcn_mfma_f32_16x16x32_f16(p0, m20[c], binacc[c], 0, 0, 0);
            binacc[c] = __builtin_amdgcn_mfma_f32_16x16x32_f16(p1, m21[c], binacc[c], 0, 0, 0);
        }
        // ---- O += P @ V (V^T [d][key], pad cols are true zeros) ----
        #pragma unroll
        for (int c = 0; c < 4; ++c) {
            o_acc[c] = __builtin_amdgcn_mfma_f32_16x16x32_f16(p0, v0r[c], o_acc[c], 0, 0, 0);
            o_acc[c] = __builtin_amdgcn_mfma_f32_16x16x32_f16(p1, v1r[c], o_acc[c], 0, 0, 0);
        }
    }

    // ---- epilogue (intra-wave): bins -> LDS, rel-V from global tables, store ----
    #pragma unroll
    for (int c = 0; c < 4; ++c) {
        const int bc = 16*c + lo;
        if (bc <= 50) {
            #pragma unroll
            for (int i = 0; i < 4; ++i) binsS[qrow+i][bc] = binacc[c][i];
        }
    }

    const int b_ = bh / NHh;
    const int h_ = bh - b_*NHh;
    #pragma unroll
    for (int i = 0; i < 4; ++i) {
        const int qr  = qrow + i;
        const int qgl = qt0 + qr;
        if (qgl >= NNq) continue;
        const float l    = binsS[qr][50];
        const float invl = 1.f / l;
        float o[4] = {o_acc[0][i], o_acc[1][i], o_acc[2][i], o_acc[3][i]};
        if (qgl == 0) {
            #pragma unroll
            for (int c = 0; c < 4; ++c) {
                const int d = 16*c + lo;
                o[c] += l * (tvv[d] + tvh[d]);
            }
        } else {
            #pragma unroll
            for (int bin = 0; bin < 24; ++bin) {
                const float wq = binsS[qr][bin];
                int dv = bin - qv_[i]; dv = min(14, max(-14, dv));
                const float* tb = tvv + (dv+15)*HD;
                #pragma unroll
                for (int c = 0; c < 4; ++c) o[c] += wq * tb[16*c + lo];
            }
            {
                const float wq = binsS[qr][24];
                #pragma unroll
                for (int c = 0; c < 4; ++c) o[c] += wq * tvv[16*c + lo];
            }
            #pragma unroll
            for (int bin = 0; bin < 24; ++bin) {
                const float wq = binsS[qr][25+bin];
                int dh = bin - qh_[i]; dh = min(14, max(-14, dh));
                const float* tb = tvh + (dh+15)*HD;
                #pragma unroll
                for (int c = 0; c < 4; ++c) o[c] += wq * tb[16*c + lo];
            }
            {
                const float wq = binsS[qr][49];
                #pragma unroll
                for (int c = 0; c < 4; ++c) o[c] += wq * tvh[16*c + lo];
            }
        }
        float* dst = ao + (size_t)(b_*NNq + qgl)*DIMM + h_*HD;
        #pragma unroll
        for (int c = 0; c < 4; ++c) dst[16*c + lo] = o[c] * invl;
    }
}

// ---------------------------------------------------------------- launcher
extern "C" void kernel_launch(void* const* d_in, const int* in_sizes, int n_in,
                              void* d_out, int out_size, void* d_ws, size_t ws_size,
                              hipStream_t stream)
{
    const float* x      = (const float*)d_in[0];
    const float* qkv_w  = (const float*)d_in[1];
    const float* proj_w = (const float*)d_in[2];
    const float* proj_b = (const float*)d_in[3];
    const float* tkv    = (const float*)d_in[4];
    const float* tkh    = (const float*)d_in[5];
    const float* tvv    = (const float*)d_in[6];
    const float* tvh    = (const float*)d_in[7];
    float* out = (float*)d_out;
    float* ws  = (float*)d_ws;

    const size_t KV = (size_t)BB * NHh * NPAD * HD;      // 7,864,320 halves per tensor
    _Float16* qh  = (_Float16*)ws;
    _Float16* kh  = qh + KV;
    _Float16* vh  = kh + KV;
    float*    ao  = (float*)(vh + KV);
    _Float16* M2g = (_Float16*)(ao + (size_t)MM*DIMM);

    dim3 b256(256, 1, 1);
    // 40960 mask entries + 786432 V-pad zeros = 827392 = 3232 * 256
    mask_init<<<3232, b256, 0, stream>>>(M2g, vh);

    dim3 g1(2304/128, (MM + 127)/128, 1);                // 18 x 73
    qkv_gemm<<<g1, b256, 0, stream>>>(x, qkv_w, qh, kh, vh);

    // 192 heads x 37 q-tiles (16 rows each), 1 wave per block
    attn_fused<<<dim3(7104,1,1), dim3(64,1,1), 0, stream>>>(qh, kh, vh, tkv, tkh, tvv, tvh, M2g, ao);

    dim3 g3(DIMM/128, (MM + 127)/128, 1);                // 6 x 73
    proj_gemm<<<g3, b256, 0, stream>>>(ao, proj_w, proj_b, out);
}

// Round 9
// 592.779 us; speedup vs baseline: 1.5003x; 1.5003x over previous
//
#include <hip/hip_runtime.h>

// Attention_11845519803093 — R15: R12 (E·M1^T on MFMA pipe) + asm-pinned batching.
//   Diagnosis R8/R12/R13/R14: hipcc remats batched loads (or spills) instead of
//   holding high VGPR. Fix: asm volatile anchors make all 32 fragments
//   simultaneously live -> allocator MUST keep them in registers.
//   * anchor 1 (after load batch, "memory"): all loads issued; waits K+M1 only.
//   * anchor 2 (after exp):                  waits V+M2 (latency hidden under S+exp).
//   * S = Q·K^T + E·M1^T (bias on matrix pipe; VALU/iter = exp2+cvt only)
//   * exp2 path (Q prescaled 0.125*log2e in qkv_gemm; propagates to qrel).
//   * 1920 blocks x 256 thr, (256,2) — R11's proven frame. Zero loop barriers.
// ws layout: qh | kh | vh (fp16) | ao (fp32) | M1 | M2

#define BB    16
#define NNq   577
#define DIMM  768
#define NHh   12
#define HD    64
#define MM    9232
#define QT    64
#define KT    64
#define NPAD  640

typedef _Float16 h8 __attribute__((ext_vector_type(8)));
typedef float    f4 __attribute__((ext_vector_type(4)));

__device__ inline h8 pack8(float4 a, float4 b) {
    h8 r;
    r[0]=(_Float16)a.x; r[1]=(_Float16)a.y; r[2]=(_Float16)a.z; r[3]=(_Float16)a.w;
    r[4]=(_Float16)b.x; r[5]=(_Float16)b.y; r[6]=(_Float16)b.z; r[7]=(_Float16)b.w;
    return r;
}

// ---------------------------------------------------------------- mask tables + V pad fill
__global__ void mask_init(_Float16* __restrict__ M1g, _Float16* __restrict__ M2g,
                          _Float16* __restrict__ vh)
{
    const int id = blockIdx.x*256 + threadIdx.x;
    if (id < NPAD*64) {
        const int key = id >> 6, bin = id & 63;
        int vb = 255, hb = 255;
        if (key == 0)      { vb = 24; hb = 49; }
        else if (key < NNq){ const int kq = key-1, kv = kq/24; vb = kv; hb = 25 + (kq - kv*24); }
        M1g[id] = (bin==vb || bin==hb) ? (_Float16)1.f : (_Float16)0.f;
        M2g[bin*NPAD + key] =
            ((key < NNq) && (bin==vb || bin==hb || bin==50)) ? (_Float16)1.f : (_Float16)0.f;
    }
    const int vid = id - NPAD*64;
    if (vid >= 0 && vid < BB*NHh*HD*64) {
        const int head = vid >> 12;
        const int rem  = vid & 4095;
        const int d    = rem >> 6;
        const int col  = 576 + (rem & 63);
        vh[(size_t)head*(HD*NPAD) + (size_t)d*NPAD + col] = (_Float16)0.f;
    }
}

// ---------------------------------------------------------------- split-fp16 MFMA GEMM core
template <typename F>
__device__ __forceinline__ void gemm128(const float* __restrict__ Amat,
                                        const float* __restrict__ Bmat,
                                        F epi)
{
    __shared__ _Float16 Ah[128][40], Al[128][40], Bh[128][40], Bl[128][40];
    const int t  = threadIdx.x;
    const int wv = t >> 6, lane = t & 63, lo = lane & 15, g = lane >> 4;
    const int wm = (wv >> 1) << 6, wn = (wv & 1) << 6;
    const int bm = blockIdx.y << 7, bn = blockIdx.x << 7;
    f4 acc[4][4] = {};
    const int lr = t >> 1;
    const int lc = (t & 1) << 4;
    const int am = bm + lr;
    const bool aok = am < MM;
    const float* arow = Amat + (size_t)(aok ? am : 0) * DIMM + lc;
    const float* brow = Bmat + (size_t)(bn + lr) * DIMM + lc;

    for (int k0 = 0; k0 < DIMM; k0 += 32) {
        float4 a0 = make_float4(0,0,0,0), a1 = a0, a2 = a0, a3 = a0;
        if (aok) {
            a0 = *(const float4*)(arow + k0);      a1 = *(const float4*)(arow + k0 + 4);
            a2 = *(const float4*)(arow + k0 + 8);  a3 = *(const float4*)(arow + k0 + 12);
        }
        const float4 b0 = *(const float4*)(brow + k0);
        const float4 b1 = *(const float4*)(brow + k0 + 4);
        const float4 b2 = *(const float4*)(brow + k0 + 8);
        const float4 b3 = *(const float4*)(brow + k0 + 12);
        __syncthreads();
        {
            const h8 ah0 = pack8(a0, a1), ah1 = pack8(a2, a3);
            float4 r0, r1, r2, r3;
            r0.x=a0.x-(float)ah0[0]; r0.y=a0.y-(float)ah0[1]; r0.z=a0.z-(float)ah0[2]; r0.w=a0.w-(float)ah0[3];
            r1.x=a1.x-(float)ah0[4]; r1.y=a1.y-(float)ah0[5]; r1.z=a1.z-(float)ah0[6]; r1.w=a1.w-(float)ah0[7];
            r2.x=a2.x-(float)ah1[0]; r2.y=a2.y-(float)ah1[1]; r2.z=a2.z-(float)ah1[2]; r2.w=a2.w-(float)ah1[3];
            r3.x=a3.x-(float)ah1[4]; r3.y=a3.y-(float)ah1[5]; r3.z=a3.z-(float)ah1[6]; r3.w=a3.w-(float)ah1[7];
            *(h8*)&Ah[lr][lc]   = ah0;  *(h8*)&Ah[lr][lc+8] = ah1;
            *(h8*)&Al[lr][lc]   = pack8(r0, r1);
            *(h8*)&Al[lr][lc+8] = pack8(r2, r3);
        }
        {
            const h8 bh0 = pack8(b0, b1), bh1 = pack8(b2, b3);
            float4 r0, r1, r2, r3;
            r0.x=b0.x-(float)bh0[0]; r0.y=b0.y-(float)bh0[1]; r0.z=b0.z-(float)bh0[2]; r0.w=b0.w-(float)bh0[3];
            r1.x=b1.x-(float)bh0[4]; r1.y=b1.y-(float)bh0[5]; r1.z=b1.z-(float)bh0[6]; r1.w=b1.w-(float)bh0[7];
            r2.x=b2.x-(float)bh1[0]; r2.y=b2.y-(float)bh1[1]; r2.z=b2.z-(float)bh1[2]; r2.w=b2.w-(float)bh1[3];
            r3.x=b3.x-(float)bh1[4]; r3.y=b3.y-(float)bh1[5]; r3.z=b3.z-(float)bh1[6]; r3.w=b3.w-(float)bh1[7];
            *(h8*)&Bh[lr][lc]   = bh0;  *(h8*)&Bh[lr][lc+8] = bh1;
            *(h8*)&Bl[lr][lc]   = pack8(r0, r1);
            *(h8*)&Bl[lr][lc+8] = pack8(r2, r3);
        }
        __syncthreads();
        h8 fah[4], fal[4], fbh[4], fbl[4];
        #pragma unroll
        for (int i = 0; i < 4; ++i) {
            fah[i] = *(const h8*)&Ah[wm + 16*i + lo][g<<3];
            fal[i] = *(const h8*)&Al[wm + 16*i + lo][g<<3];
            fbh[i] = *(const h8*)&Bh[wn + 16*i + lo][g<<3];
            fbl[i] = *(const h8*)&Bl[wn + 16*i + lo][g<<3];
        }
        #pragma unroll
        for (int mi = 0; mi < 4; ++mi) {
            #pragma unroll
            for (int ni = 0; ni < 4; ++ni) {
                acc[mi][ni] = __builtin_amdgcn_mfma_f32_16x16x32_f16(fah[mi], fbh[ni], acc[mi][ni], 0, 0, 0);
                acc[mi][ni] = __builtin_amdgcn_mfma_f32_16x16x32_f16(fah[mi], fbl[ni], acc[mi][ni], 0, 0, 0);
                acc[mi][ni] = __builtin_amdgcn_mfma_f32_16x16x32_f16(fal[mi], fbh[ni], acc[mi][ni], 0, 0, 0);
            }
        }
    }
    epi(acc, bm, bn, wm, wn, lo, g);
}

// ---------------------------------------------------------------- QKV GEMM (MFMA)
__global__ __launch_bounds__(256, 2)
void qkv_gemm(const float* __restrict__ x, const float* __restrict__ w,
              _Float16* __restrict__ qh, _Float16* __restrict__ kh, _Float16* __restrict__ vh)
{
    gemm128(x, w, [=](f4 (&acc)[4][4], int bm, int bn, int wm, int wn, int lo, int g) {
        const int three = bn / 768;
        const int cb    = bn - three * 768;
        #pragma unroll
        for (int mi = 0; mi < 4; ++mi) {
            #pragma unroll
            for (int reg = 0; reg < 4; ++reg) {
                const int m = bm + wm + 16*mi + 4*g + reg;
                if (m >= MM) continue;
                const int b_ = m / NNq;
                const int n_ = m - b_ * NNq;
                #pragma unroll
                for (int ni = 0; ni < 4; ++ni) {
                    const int n  = cb + wn + 16*ni + lo;
                    const int hh = n >> 6;
                    const int d  = n & 63;
                    if (three == 0) {
                        // Q fp16 [head][640][64], scaled by 0.125*log2(e) for exp2 path
                        qh[((size_t)(b_*NHh + hh)*NPAD + n_)*HD + d] =
                            (_Float16)(acc[mi][ni][reg] * 0.18033688f);
                    } else if (three == 1) {
                        kh[((size_t)(b_*NHh + hh)*NPAD + n_)*HD + d] = (_Float16)acc[mi][ni][reg];
                    } else {
                        vh[((size_t)(b_*NHh + hh)*HD + d)*NPAD + n_] = (_Float16)acc[mi][ni][reg];
                    }
                }
            }
        }
    });
}

// ---------------------------------------------------------------- proj GEMM (MFMA)
__global__ __launch_bounds__(256, 2)
void proj_gemm(const float* __restrict__ A, const float* __restrict__ w,
               const float* __restrict__ bias, float* __restrict__ out)
{
    gemm128(A, w, [=](f4 (&acc)[4][4], int bm, int bn, int wm, int wn, int lo, int g) {
        #pragma unroll
        for (int ni = 0; ni < 4; ++ni) {
            const int n  = bn + wn + 16*ni + lo;
            const float bb = bias[n];
            #pragma unroll
            for (int mi = 0; mi < 4; ++mi) {
                #pragma unroll
                for (int reg = 0; reg < 4; ++reg) {
                    const int m = bm + wm + 16*mi + 4*g + reg;
                    if (m >= MM) continue;
                    out[(size_t)m*DIMM + n] = acc[mi][ni][reg] + bb;
                }
            }
        }
    });
}

// ---------------------------------------------------------------- fused attention v13
__global__ __launch_bounds__(256, 2)
void attn_fused(const _Float16* __restrict__ qh,
                const _Float16* __restrict__ kh, const _Float16* __restrict__ vh,
                const float* __restrict__ tkv, const float* __restrict__ tkh,
                const float* __restrict__ tvv, const float* __restrict__ tvh,
                const _Float16* __restrict__ M1g, const _Float16* __restrict__ M2g,
                float* __restrict__ ao)
{
    // LDS 43248 B:
    //   [    0, 9216) qrelS fp16 [64][72]  (prologue only; intra-wave)
    //   [ 9216,18432) Pt    fp16 [64][72]  (loop; intra-wave)
    //   [18432,27648) Ee    fp16 [64][72]  (built per-wave; read as frags)
    //   [27648,43248) TvS   fp32 [60][65]
    //   epilogue: binsS fp32 [64][52] at 0 (13312 B; qrelS/Pt dead by then)
    __shared__ __align__(16) char smem[43248];
    _Float16 (*qrelS)[72] = (_Float16(*)[72])(smem);
    _Float16 (*Pt)[72]    = (_Float16(*)[72])(smem + 9216);
    _Float16 (*Ee)[72]    = (_Float16(*)[72])(smem + 18432);
    float    (*TvS)[65]   = (float(*)[65])(smem + 27648);
    float    (*binsS)[52] = (float(*)[52])(smem);

    const int t    = threadIdx.x;
    const int w    = t >> 6;
    const int lane = t & 63;
    const int lo   = lane & 15;
    const int g    = lane >> 4;
    const int gb   = g << 3;

    // ---- XCD-chunked decode: head % 8 == block % 8 -> one head per XCD L2 ----
    const int blk = blockIdx.x;            // 0..1919
    const int x8  = blk & 7;
    const int r_  = blk >> 3;              // 0..239
    const int hq  = r_ / 10;               // 0..23
    const int qt  = r_ - hq*10;            // 0..9
    const int bh  = x8 + (hq << 3);        // head 0..191, bh%8 == x8
    const int qt0 = qt * QT;
    const int qrow = 16*w + 4*g;
    const _Float16* qp = qh + (size_t)bh * (NPAD*HD);
    const _Float16* kp = kh + (size_t)bh * (NPAD*HD);
    const _Float16* vp = vh + (size_t)bh * (HD*NPAD);

    // ---- stage tvv/tvh fp32 -> TvS (read only after the epilogue barrier) ----
    for (int e = t; e < 60*64; e += 256) {
        const int r = e >> 6, d = e & 63;
        TvS[r][d] = (r < 30) ? tvv[r*HD + d] : tvh[(r-30)*HD + d];
    }

    // ---- Q fragments straight from global (qh fp16 [640][64], log2-prescaled) ----
    const h8 a0 = *(const h8*)(qp + (size_t)(qt0 + 16*w + lo)*HD + gb);
    const h8 a1 = *(const h8*)(qp + (size_t)(qt0 + 16*w + lo)*HD + 32 + gb);

    // ---- qrel = Q @ T^T via MFMA (64 q x 60 r x 64 d); intra-wave rows ----
    {
        f4 qacc[4] = {f4{0,0,0,0}, f4{0,0,0,0}, f4{0,0,0,0}, f4{0,0,0,0}};
        #pragma unroll
        for (int c = 0; c < 4; ++c) {
            const int r16 = 16*c + lo;
            const float* src = (r16 < 30) ? (tkv + r16*HD) : (tkh + (r16-30)*HD);
            h8 tb0 = {}, tb1 = {};
            if (r16 < 60) {
                tb0 = pack8(*(const float4*)(src + gb),      *(const float4*)(src + gb + 4));
                tb1 = pack8(*(const float4*)(src + 32 + gb), *(const float4*)(src + 32 + gb + 4));
            }
            qacc[c] = __builtin_amdgcn_mfma_f32_16x16x32_f16(a0, tb0, qacc[c], 0, 0, 0);
            qacc[c] = __builtin_amdgcn_mfma_f32_16x16x32_f16(a1, tb1, qacc[c], 0, 0, 0);
        }
        #pragma unroll
        for (int c = 0; c < 4; ++c) {
            #pragma unroll
            for (int i = 0; i < 4; ++i)
                qrelS[qrow + i][16*c + lo] = (_Float16)qacc[c][i];
        }
    }
    // NO barrier: Ee build below reads only this wave's own 16 rows.

    // ---- build Ee[q][bin] per-wave (rows 16w..16w+15) ----
    for (int e = lane; e < 16*64; e += 64) {
        const int q_  = 16*w + (e >> 6);
        const int bin = e & 63;
        const int qgl = qt0 + q_;
        _Float16 val = (_Float16)0.f;
        if (qgl < NNq && bin < 50) {
            if (qgl == 0) {
                val = (bin <= 24) ? qrelS[q_][0] : qrelS[q_][30];
            } else {
                const int qq = qgl - 1;
                const int qv = qq / 24;
                const int qh2 = qq - qv*24;
                if (bin < 24) {
                    int dv = bin - qv; dv = min(14, max(-14, dv));
                    val = qrelS[q_][dv + 15];
                } else if (bin == 24) {
                    val = qrelS[q_][0];
                } else if (bin < 49) {
                    int dh = (bin - 25) - qh2; dh = min(14, max(-14, dh));
                    val = qrelS[q_][30 + dh + 15];
                } else {
                    val = qrelS[q_][30];
                }
            }
        }
        Ee[q_][bin] = val;
    }
    // NO barrier: e-fragment reads below are this wave's own rows.
    const h8 e0 = *(const h8*)&Ee[16*w + lo][gb];
    const h8 e1 = *(const h8*)&Ee[16*w + lo][32 + gb];

    int qv_[4], qh_[4];
    #pragma unroll
    for (int i = 0; i < 4; ++i) {
        const int qgl = qt0 + qrow + i;
        int qq = qgl - 1; if (qq < 0) qq = 0;
        qv_[i] = qq / 24;
        qh_[i] = qq - qv_[i]*24;
    }

    f4 o_acc [4] = {f4{0,0,0,0}, f4{0,0,0,0}, f4{0,0,0,0}, f4{0,0,0,0}};
    f4 binacc[4] = {f4{0,0,0,0}, f4{0,0,0,0}, f4{0,0,0,0}, f4{0,0,0,0}};

    // ================= barrier-free K loop =================
    for (int kt0 = 0; kt0 < NNq; kt0 += KT) {
        // ---- batch-issue ALL global fragment loads for this tile ----
        h8 kb0[4], kb1[4], m10[4], m11[4], v0r[4], v1r[4], m20[4], m21[4];
        #pragma unroll
        for (int c = 0; c < 4; ++c) {
            const int key = kt0 + 16*c + lo;
            kb0[c] = *(const h8*)(kp + (size_t)key*HD + gb);
            kb1[c] = *(const h8*)(kp + (size_t)key*HD + 32 + gb);
            m10[c] = *(const h8*)(M1g + (size_t)key*64 + gb);
            m11[c] = *(const h8*)(M1g + (size_t)key*64 + 32 + gb);
        }
        #pragma unroll
        for (int c = 0; c < 4; ++c) {
            const int dd = 16*c + lo;
            v0r[c] = *(const h8*)(vp + (size_t)dd*NPAD + kt0 + gb);
            v1r[c] = *(const h8*)(vp + (size_t)dd*NPAD + kt0 + 32 + gb);
            m20[c] = *(const h8*)(M2g + (size_t)dd*NPAD + kt0 + gb);
            m21[c] = *(const h8*)(M2g + (size_t)dd*NPAD + kt0 + 32 + gb);
        }
        // ---- anchor 1: all 32 loads issued; K+M1 must be in regs here.
        //      "memory" stops V/M2 loads from sinking below this point. ----
        asm volatile("" :: "v"(kb0[0]), "v"(kb0[1]), "v"(kb0[2]), "v"(kb0[3]),
                           "v"(kb1[0]), "v"(kb1[1]), "v"(kb1[2]), "v"(kb1[3]) : "memory");
        asm volatile("" :: "v"(m10[0]), "v"(m10[1]), "v"(m10[2]), "v"(m10[3]),
                           "v"(m11[0]), "v"(m11[1]), "v"(m11[2]), "v"(m11[3]) : "memory");
        // ---- S = Q·K^T + E·M1^T (MFMA, log2 units) ----
        f4 Sc[4];
        #pragma unroll
        for (int c = 0; c < 4; ++c) {
            f4 acc = f4{0,0,0,0};
            acc = __builtin_amdgcn_mfma_f32_16x16x32_f16(a0, kb0[c], acc, 0, 0, 0);
            acc = __builtin_amdgcn_mfma_f32_16x16x32_f16(a1, kb1[c], acc, 0, 0, 0);
            acc = __builtin_amdgcn_mfma_f32_16x16x32_f16(e0, m10[c], acc, 0, 0, 0);
            acc = __builtin_amdgcn_mfma_f32_16x16x32_f16(e1, m11[c], acc, 0, 0, 0);
            Sc[c] = acc;
        }
        // ---- P = exp2(S), zero pad-key columns ----
        #pragma unroll
        for (int c = 0; c < 4; ++c) {
            const bool ok = (kt0 + 16*c + lo) < NNq;
            #pragma unroll
            for (int i = 0; i < 4; ++i) {
                const float p = ok ? exp2f(Sc[c][i]) : 0.f;
                Pt[qrow+i][16*c + lo] = (_Float16)p;
            }
        }
        // ---- P fragments (own wave's rows; lgkmcnt ordering only) ----
        const h8 p0 = *(const h8*)&Pt[16*w + lo][gb];
        const h8 p1 = *(const h8*)&Pt[16*w + lo][32 + gb];
        // ---- anchor 2: V+M2 now required (latency hidden under S+exp) ----
        asm volatile("" :: "v"(v0r[0]), "v"(v0r[1]), "v"(v0r[2]), "v"(v0r[3]),
                           "v"(v1r[0]), "v"(v1r[1]), "v"(v1r[2]), "v"(v1r[3]) : "memory");
        asm volatile("" :: "v"(m20[0]), "v"(m20[1]), "v"(m20[2]), "v"(m20[3]),
                           "v"(m21[0]), "v"(m21[1]), "v"(m21[2]), "v"(m21[3]) : "memory");
        // ---- bins += P @ M2^T ----
        #pragma unroll
        for (int c = 0; c < 4; ++c) {
            binacc[c] = __builtin_amdgcn_mfma_f32_16x16x32_f16(p0, m20[c], binacc[c], 0, 0, 0);
            binacc[c] = __builtin_amdgcn_mfma_f32_16x16x32_f16(p1, m21[c], binacc[c], 0, 0, 0);
        }
        // ---- O += P @ V  (V^T [d][key], pad cols are true zeros) ----
        #pragma unroll
        for (int c = 0; c < 4; ++c) {
            o_acc[c] = __builtin_amdgcn_mfma_f32_16x16x32_f16(p0, v0r[c], o_acc[c], 0, 0, 0);
            o_acc[c] = __builtin_amdgcn_mfma_f32_16x16x32_f16(p1, v1r[c], o_acc[c], 0, 0, 0);
        }
    }

    // ---- epilogue: bins -> LDS, rel-V from TvS, normalize, store ----
    __syncthreads();                                    // all waves done with loop LDS
    #pragma unroll
    for (int c = 0; c < 4; ++c) {
        const int bc = 16*c + lo;
        if (bc <= 50) {
            #pragma unroll
            for (int i = 0; i < 4; ++i) binsS[qrow+i][bc] = binacc[c][i];
        }
    }
    __syncthreads();

    const int b_ = bh / NHh;
    const int h_ = bh - b_*NHh;
    #pragma unroll
    for (int i = 0; i < 4; ++i) {
        const int qr  = qrow + i;
        const int qgl = qt0 + qr;
        if (qgl >= NNq) continue;
        const float l    = binsS[qr][50];
        const float invl = 1.f / l;
        float o[4] = {o_acc[0][i], o_acc[1][i], o_acc[2][i], o_acc[3][i]};
        if (qgl == 0) {
            #pragma unroll
            for (int c = 0; c < 4; ++c) {
                const int d = 16*c + lo;
                o[c] += l * (TvS[0][d] + TvS[30][d]);
            }
        } else {
            #pragma unroll
            for (int bin = 0; bin < 24; ++bin) {
                const float wq = binsS[qr][bin];
                int dv = bin - qv_[i]; dv = min(14, max(-14, dv));
                #pragma unroll
                for (int c = 0; c < 4; ++c) o[c] += wq * TvS[dv+15][16*c + lo];
            }
            {
                const float wq = binsS[qr][24];
                #pragma unroll
                for (int c = 0; c < 4; ++c) o[c] += wq * TvS[0][16*c + lo];
            }
            #pragma unroll
            for (int bin = 0; bin < 24; ++bin) {
                const float wq = binsS[qr][25+bin];
                int dh = bin - qh_[i]; dh = min(14, max(-14, dh));
                #pragma unroll
                for (int c = 0; c < 4; ++c) o[c] += wq * TvS[45+dh][16*c + lo];
            }
            {
                const float wq = binsS[qr][49];
                #pragma unroll
                for (int c = 0; c < 4; ++c) o[c] += wq * TvS[30][16*c + lo];
            }
        }
        float* dst = ao + (size_t)(b_*NNq + qgl)*DIMM + h_*HD;
        #pragma unroll
        for (int c = 0; c < 4; ++c) dst[16*c + lo] = o[c] * invl;
    }
}

// ---------------------------------------------------------------- launcher
extern "C" void kernel_launch(void* const* d_in, const int* in_sizes, int n_in,
                              void* d_out, int out_size, void* d_ws, size_t ws_size,
                              hipStream_t stream)
{
    const float* x      = (const float*)d_in[0];
    const float* qkv_w  = (const float*)d_in[1];
    const float* proj_w = (const float*)d_in[2];
    const float* proj_b = (const float*)d_in[3];
    const float* tkv    = (const float*)d_in[4];
    const float* tkh    = (const float*)d_in[5];
    const float* tvv    = (const float*)d_in[6];
    const float* tvh    = (const float*)d_in[7];
    float* out = (float*)d_out;
    float* ws  = (float*)d_ws;

    const size_t KV = (size_t)BB * NHh * NPAD * HD;      // 7,864,320 halves per tensor
    _Float16* qh  = (_Float16*)ws;
    _Float16* kh  = qh + KV;
    _Float16* vh  = kh + KV;
    float*    ao  = (float*)(vh + KV);
    _Float16* M1g = (_Float16*)(ao + (size_t)MM*DIMM);
    _Float16* M2g = M1g + NPAD*64;

    dim3 b256(256, 1, 1);
    // 40960 mask entries + 786432 V-pad zeros = 827392 = 3232 * 256
    mask_init<<<3232, b256, 0, stream>>>(M1g, M2g, vh);

    dim3 g1(2304/128, (MM + 127)/128, 1);                // 18 x 73
    qkv_gemm<<<g1, b256, 0, stream>>>(x, qkv_w, qh, kh, vh);

    attn_fused<<<dim3(1920,1,1), b256, 0, stream>>>(qh, kh, vh, tkv, tkh, tvv, tvh, M1g, M2g, ao);

    dim3 g3(DIMM/128, (MM + 127)/128, 1);                // 6 x 73
    proj_gemm<<<g3, b256, 0, stream>>>(ao, proj_w, proj_b, out);
}

// Round 10
// 536.450 us; speedup vs baseline: 1.6578x; 1.1050x over previous
//
#include <hip/hip_runtime.h>

// Attention_11845519803093 — R16: attn = R11 verbatim (verified 264us);
//   GEMM split hoisted to a prepass.
//   * split_pass: x, qkv_w -> fp16 hi/lo pairs ONCE (was recomputed 18x/73x
//     inside gemm128's staging, ~100 VALU per 16B staged, between barriers).
//   * gemm128h: stages pre-split fp16 via pure 16B h8 copies; zero conversion
//     VALU; same MFMA loop -> same numerics.
//   * proj_gemm unchanged (old fp32-split path) this round.
// ws layout: qh | kh | vh | ao | M2 | xh | xl | wh | wl

#define BB    16
#define NNq   577
#define DIMM  768
#define NHh   12
#define HD    64
#define MM    9232
#define QT    64
#define KT    64
#define NPAD  640
#define NW3   2304

typedef _Float16 h8 __attribute__((ext_vector_type(8)));
typedef _Float16 h4 __attribute__((ext_vector_type(4)));
typedef float    f4 __attribute__((ext_vector_type(4)));

__device__ inline h8 pack8(float4 a, float4 b) {
    h8 r;
    r[0]=(_Float16)a.x; r[1]=(_Float16)a.y; r[2]=(_Float16)a.z; r[3]=(_Float16)a.w;
    r[4]=(_Float16)b.x; r[5]=(_Float16)b.y; r[6]=(_Float16)b.z; r[7]=(_Float16)b.w;
    return r;
}

// ---------------------------------------------------------------- mask table + V pad fill
__global__ void mask_init(_Float16* __restrict__ M2g, _Float16* __restrict__ vh)
{
    const int id = blockIdx.x*256 + threadIdx.x;
    if (id < NPAD*64) {
        const int key = id >> 6, bin = id & 63;
        int vb = 255, hb = 255;
        if (key == 0)      { vb = 24; hb = 49; }
        else if (key < NNq){ const int kq = key-1, kv = kq/24; vb = kv; hb = 25 + (kq - kv*24); }
        M2g[bin*NPAD + key] =
            ((key < NNq) && (bin==vb || bin==hb || bin==50)) ? (_Float16)1.f : (_Float16)0.f;
    }
    const int vid = id - NPAD*64;
    if (vid >= 0 && vid < BB*NHh*HD*64) {
        const int head = vid >> 12;
        const int rem  = vid & 4095;
        const int d    = rem >> 6;
        const int col  = 576 + (rem & 63);
        vh[(size_t)head*(HD*NPAD) + (size_t)d*NPAD + col] = (_Float16)0.f;
    }
}

// ---------------------------------------------------------------- fp32 -> fp16 hi/lo prepass
__global__ void split_pass(const float* __restrict__ x, const float* __restrict__ w,
                           _Float16* __restrict__ xh, _Float16* __restrict__ xl,
                           _Float16* __restrict__ wh, _Float16* __restrict__ wl)
{
    const size_t NX = (size_t)MM*DIMM/4;        // 1,772,544 float4s
    const size_t NWq = (size_t)NW3*DIMM/4;      //   442,368 float4s
    const size_t id = (size_t)blockIdx.x*256 + threadIdx.x;
    if (id < NX) {
        const float4 v = ((const float4*)x)[id];
        h4 hh; hh[0]=(_Float16)v.x; hh[1]=(_Float16)v.y; hh[2]=(_Float16)v.z; hh[3]=(_Float16)v.w;
        h4 ll; ll[0]=(_Float16)(v.x-(float)hh[0]); ll[1]=(_Float16)(v.y-(float)hh[1]);
               ll[2]=(_Float16)(v.z-(float)hh[2]); ll[3]=(_Float16)(v.w-(float)hh[3]);
        ((h4*)xh)[id] = hh; ((h4*)xl)[id] = ll;
    } else if (id < NX + NWq) {
        const size_t j = id - NX;
        const float4 v = ((const float4*)w)[j];
        h4 hh; hh[0]=(_Float16)v.x; hh[1]=(_Float16)v.y; hh[2]=(_Float16)v.z; hh[3]=(_Float16)v.w;
        h4 ll; ll[0]=(_Float16)(v.x-(float)hh[0]); ll[1]=(_Float16)(v.y-(float)hh[1]);
               ll[2]=(_Float16)(v.z-(float)hh[2]); ll[3]=(_Float16)(v.w-(float)hh[3]);
        ((h4*)wh)[j] = hh; ((h4*)wl)[j] = ll;
    }
}

// ---------------------------------------------------------------- pre-split fp16 MFMA GEMM core
template <typename F>
__device__ __forceinline__ void gemm128h(const _Float16* __restrict__ Ah_g,
                                         const _Float16* __restrict__ Al_g,
                                         const _Float16* __restrict__ Bh_g,
                                         const _Float16* __restrict__ Bl_g,
                                         F epi)
{
    __shared__ _Float16 Ah[128][40], Al[128][40], Bh[128][40], Bl[128][40];
    const int t  = threadIdx.x;
    const int wv = t >> 6, lane = t & 63, lo = lane & 15, g = lane >> 4;
    const int wm = (wv >> 1) << 6, wn = (wv & 1) << 6;
    const int bm = blockIdx.y << 7, bn = blockIdx.x << 7;
    f4 acc[4][4] = {};
    const int lr = t >> 1;
    const int lc = (t & 1) << 4;
    const int am = bm + lr;
    const bool aok = am < MM;
    const _Float16* arh = Ah_g + (size_t)(aok ? am : 0) * DIMM + lc;
    const _Float16* arl = Al_g + (size_t)(aok ? am : 0) * DIMM + lc;
    const _Float16* brh = Bh_g + (size_t)(bn + lr) * DIMM + lc;
    const _Float16* brl = Bl_g + (size_t)(bn + lr) * DIMM + lc;

    for (int k0 = 0; k0 < DIMM; k0 += 32) {
        h8 a_h0 = {}, a_h1 = {}, a_l0 = {}, a_l1 = {};
        if (aok) {
            a_h0 = *(const h8*)(arh + k0); a_h1 = *(const h8*)(arh + k0 + 8);
            a_l0 = *(const h8*)(arl + k0); a_l1 = *(const h8*)(arl + k0 + 8);
        }
        const h8 b_h0 = *(const h8*)(brh + k0), b_h1 = *(const h8*)(brh + k0 + 8);
        const h8 b_l0 = *(const h8*)(brl + k0), b_l1 = *(const h8*)(brl + k0 + 8);
        __syncthreads();
        *(h8*)&Ah[lr][lc]   = a_h0;  *(h8*)&Ah[lr][lc+8] = a_h1;
        *(h8*)&Al[lr][lc]   = a_l0;  *(h8*)&Al[lr][lc+8] = a_l1;
        *(h8*)&Bh[lr][lc]   = b_h0;  *(h8*)&Bh[lr][lc+8] = b_h1;
        *(h8*)&Bl[lr][lc]   = b_l0;  *(h8*)&Bl[lr][lc+8] = b_l1;
        __syncthreads();
        h8 fah[4], fal[4], fbh[4], fbl[4];
        #pragma unroll
        for (int i = 0; i < 4; ++i) {
            fah[i] = *(const h8*)&Ah[wm + 16*i + lo][g<<3];
            fal[i] = *(const h8*)&Al[wm + 16*i + lo][g<<3];
            fbh[i] = *(const h8*)&Bh[wn + 16*i + lo][g<<3];
            fbl[i] = *(const h8*)&Bl[wn + 16*i + lo][g<<3];
        }
        #pragma unroll
        for (int mi = 0; mi < 4; ++mi) {
            #pragma unroll
            for (int ni = 0; ni < 4; ++ni) {
                acc[mi][ni] = __builtin_amdgcn_mfma_f32_16x16x32_f16(fah[mi], fbh[ni], acc[mi][ni], 0, 0, 0);
                acc[mi][ni] = __builtin_amdgcn_mfma_f32_16x16x32_f16(fah[mi], fbl[ni], acc[mi][ni], 0, 0, 0);
                acc[mi][ni] = __builtin_amdgcn_mfma_f32_16x16x32_f16(fal[mi], fbh[ni], acc[mi][ni], 0, 0, 0);
            }
        }
    }
    epi(acc, bm, bn, wm, wn, lo, g);
}

// ---------------------------------------------------------------- fp32 split-fp16 GEMM core (proj)
template <typename F>
__device__ __forceinline__ void gemm128(const float* __restrict__ Amat,
                                        const float* __restrict__ Bmat,
                                        F epi)
{
    __shared__ _Float16 Ah[128][40], Al[128][40], Bh[128][40], Bl[128][40];
    const int t  = threadIdx.x;
    const int wv = t >> 6, lane = t & 63, lo = lane & 15, g = lane >> 4;
    const int wm = (wv >> 1) << 6, wn = (wv & 1) << 6;
    const int bm = blockIdx.y << 7, bn = blockIdx.x << 7;
    f4 acc[4][4] = {};
    const int lr = t >> 1;
    const int lc = (t & 1) << 4;
    const int am = bm + lr;
    const bool aok = am < MM;
    const float* arow = Amat + (size_t)(aok ? am : 0) * DIMM + lc;
    const float* brow = Bmat + (size_t)(bn + lr) * DIMM + lc;

    for (int k0 = 0; k0 < DIMM; k0 += 32) {
        float4 a0 = make_float4(0,0,0,0), a1 = a0, a2 = a0, a3 = a0;
        if (aok) {
            a0 = *(const float4*)(arow + k0);      a1 = *(const float4*)(arow + k0 + 4);
            a2 = *(const float4*)(arow + k0 + 8);  a3 = *(const float4*)(arow + k0 + 12);
        }
        const float4 b0 = *(const float4*)(brow + k0);
        const float4 b1 = *(const float4*)(brow + k0 + 4);
        const float4 b2 = *(const float4*)(brow + k0 + 8);
        const float4 b3 = *(const float4*)(brow + k0 + 12);
        __syncthreads();
        {
            const h8 ah0 = pack8(a0, a1), ah1 = pack8(a2, a3);
            float4 r0, r1, r2, r3;
            r0.x=a0.x-(float)ah0[0]; r0.y=a0.y-(float)ah0[1]; r0.z=a0.z-(float)ah0[2]; r0.w=a0.w-(float)ah0[3];
            r1.x=a1.x-(float)ah0[4]; r1.y=a1.y-(float)ah0[5]; r1.z=a1.z-(float)ah0[6]; r1.w=a1.w-(float)ah0[7];
            r2.x=a2.x-(float)ah1[0]; r2.y=a2.y-(float)ah1[1]; r2.z=a2.z-(float)ah1[2]; r2.w=a2.w-(float)ah1[3];
            r3.x=a3.x-(float)ah1[4]; r3.y=a3.y-(float)ah1[5]; r3.z=a3.z-(float)ah1[6]; r3.w=a3.w-(float)ah1[7];
            *(h8*)&Ah[lr][lc]   = ah0;  *(h8*)&Ah[lr][lc+8] = ah1;
            *(h8*)&Al[lr][lc]   = pack8(r0, r1);
            *(h8*)&Al[lr][lc+8] = pack8(r2, r3);
        }
        {
            const h8 bh0 = pack8(b0, b1), bh1 = pack8(b2, b3);
            float4 r0, r1, r2, r3;
            r0.x=b0.x-(float)bh0[0]; r0.y=b0.y-(float)bh0[1]; r0.z=b0.z-(float)bh0[2]; r0.w=b0.w-(float)bh0[3];
            r1.x=b1.x-(float)bh0[4]; r1.y=b1.y-(float)bh0[5]; r1.z=b1.z-(float)bh0[6]; r1.w=b1.w-(float)bh0[7];
            r2.x=b2.x-(float)bh1[0]; r2.y=b2.y-(float)bh1[1]; r2.z=b2.z-(float)bh1[2]; r2.w=b2.w-(float)bh1[3];
            r3.x=b3.x-(float)bh1[4]; r3.y=b3.y-(float)bh1[5]; r3.z=b3.z-(float)bh1[6]; r3.w=b3.w-(float)bh1[7];
            *(h8*)&Bh[lr][lc]   = bh0;  *(h8*)&Bh[lr][lc+8] = bh1;
            *(h8*)&Bl[lr][lc]   = pack8(r0, r1);
            *(h8*)&Bl[lr][lc+8] = pack8(r2, r3);
        }
        __syncthreads();
        h8 fah[4], fal[4], fbh[4], fbl[4];
        #pragma unroll
        for (int i = 0; i < 4; ++i) {
            fah[i] = *(const h8*)&Ah[wm + 16*i + lo][g<<3];
            fal[i] = *(const h8*)&Al[wm + 16*i + lo][g<<3];
            fbh[i] = *(const h8*)&Bh[wn + 16*i + lo][g<<3];
            fbl[i] = *(const h8*)&Bl[wn + 16*i + lo][g<<3];
        }
        #pragma unroll
        for (int mi = 0; mi < 4; ++mi) {
            #pragma unroll
            for (int ni = 0; ni < 4; ++ni) {
                acc[mi][ni] = __builtin_amdgcn_mfma_f32_16x16x32_f16(fah[mi], fbh[ni], acc[mi][ni], 0, 0, 0);
                acc[mi][ni] = __builtin_amdgcn_mfma_f32_16x16x32_f16(fah[mi], fbl[ni], acc[mi][ni], 0, 0, 0);
                acc[mi][ni] = __builtin_amdgcn_mfma_f32_16x16x32_f16(fal[mi], fbh[ni], acc[mi][ni], 0, 0, 0);
            }
        }
    }
    epi(acc, bm, bn, wm, wn, lo, g);
}

// ---------------------------------------------------------------- QKV GEMM (pre-split fp16)
__global__ __launch_bounds__(256, 2)
void qkv_gemm(const _Float16* __restrict__ xh, const _Float16* __restrict__ xl,
              const _Float16* __restrict__ wh, const _Float16* __restrict__ wl,
              _Float16* __restrict__ qh, _Float16* __restrict__ kh, _Float16* __restrict__ vh)
{
    gemm128h(xh, xl, wh, wl, [=](f4 (&acc)[4][4], int bm, int bn, int wm, int wn, int lo, int g) {
        const int three = bn / 768;
        const int cb    = bn - three * 768;
        #pragma unroll
        for (int mi = 0; mi < 4; ++mi) {
            #pragma unroll
            for (int reg = 0; reg < 4; ++reg) {
                const int m = bm + wm + 16*mi + 4*g + reg;
                if (m >= MM) continue;
                const int b_ = m / NNq;
                const int n_ = m - b_ * NNq;
                #pragma unroll
                for (int ni = 0; ni < 4; ++ni) {
                    const int n  = cb + wn + 16*ni + lo;
                    const int hh = n >> 6;
                    const int d  = n & 63;
                    if (three == 0) {
                        qh[((size_t)(b_*NHh + hh)*NPAD + n_)*HD + d] = (_Float16)(acc[mi][ni][reg] * 0.125f);
                    } else if (three == 1) {
                        kh[((size_t)(b_*NHh + hh)*NPAD + n_)*HD + d] = (_Float16)acc[mi][ni][reg];
                    } else {
                        vh[((size_t)(b_*NHh + hh)*HD + d)*NPAD + n_] = (_Float16)acc[mi][ni][reg];
                    }
                }
            }
        }
    });
}

// ---------------------------------------------------------------- proj GEMM (fp32 split path)
__global__ __launch_bounds__(256, 2)
void proj_gemm(const float* __restrict__ A, const float* __restrict__ w,
               const float* __restrict__ bias, float* __restrict__ out)
{
    gemm128(A, w, [=](f4 (&acc)[4][4], int bm, int bn, int wm, int wn, int lo, int g) {
        #pragma unroll
        for (int ni = 0; ni < 4; ++ni) {
            const int n  = bn + wn + 16*ni + lo;
            const float bb = bias[n];
            #pragma unroll
            for (int mi = 0; mi < 4; ++mi) {
                #pragma unroll
                for (int reg = 0; reg < 4; ++reg) {
                    const int m = bm + wm + 16*mi + 4*g + reg;
                    if (m >= MM) continue;
                    out[(size_t)m*DIMM + n] = acc[mi][ni][reg] + bb;
                }
            }
        }
    });
}

// ---------------------------------------------------------------- fused attention (R11 verbatim)
__global__ __launch_bounds__(256, 2)
void attn_fused(const _Float16* __restrict__ qh,
                const _Float16* __restrict__ kh, const _Float16* __restrict__ vh,
                const float* __restrict__ tkv, const float* __restrict__ tkh,
                const float* __restrict__ tvv, const float* __restrict__ tvh,
                const _Float16* __restrict__ M2g,
                float* __restrict__ ao)
{
    __shared__ __align__(16) char smem[34048];
    _Float16 (*qrelS)[72] = (_Float16(*)[72])(smem);
    _Float16 (*Pt)[72]    = (_Float16(*)[72])(smem + 9216);
    float    (*TvS)[65]   = (float(*)[65])(smem + 18432);
    float    (*binsS)[52] = (float(*)[52])(smem);

    const int t    = threadIdx.x;
    const int w    = t >> 6;
    const int lane = t & 63;
    const int lo   = lane & 15;
    const int g    = lane >> 4;
    const int gb   = g << 3;

    const int blk = blockIdx.x;            // 0..1919
    const int x8  = blk & 7;
    const int r_  = blk >> 3;              // 0..239
    const int hq  = r_ / 10;               // 0..23
    const int qt  = r_ - hq*10;            // 0..9
    const int bh  = x8 + (hq << 3);        // head 0..191
    const int qt0 = qt * QT;
    const int qrow = 16*w + 4*g;
    const _Float16* qp = qh + (size_t)bh * (NPAD*HD);
    const _Float16* kp = kh + (size_t)bh * (NPAD*HD);
    const _Float16* vp = vh + (size_t)bh * (HD*NPAD);

    for (int e = t; e < 60*64; e += 256) {
        const int r = e >> 6, d = e & 63;
        TvS[r][d] = (r < 30) ? tvv[r*HD + d] : tvh[(r-30)*HD + d];
    }

    const h8 a0 = *(const h8*)(qp + (size_t)(qt0 + 16*w + lo)*HD + gb);
    const h8 a1 = *(const h8*)(qp + (size_t)(qt0 + 16*w + lo)*HD + 32 + gb);

    {
        f4 qacc[4] = {f4{0,0,0,0}, f4{0,0,0,0}, f4{0,0,0,0}, f4{0,0,0,0}};
        #pragma unroll
        for (int c = 0; c < 4; ++c) {
            const int r16 = 16*c + lo;
            const float* src = (r16 < 30) ? (tkv + r16*HD) : (tkh + (r16-30)*HD);
            h8 tb0 = {}, tb1 = {};
            if (r16 < 60) {
                tb0 = pack8(*(const float4*)(src + gb),      *(const float4*)(src + gb + 4));
                tb1 = pack8(*(const float4*)(src + 32 + gb), *(const float4*)(src + 32 + gb + 4));
            }
            qacc[c] = __builtin_amdgcn_mfma_f32_16x16x32_f16(a0, tb0, qacc[c], 0, 0, 0);
            qacc[c] = __builtin_amdgcn_mfma_f32_16x16x32_f16(a1, tb1, qacc[c], 0, 0, 0);
        }
        #pragma unroll
        for (int c = 0; c < 4; ++c) {
            #pragma unroll
            for (int i = 0; i < 4; ++i)
                qrelS[qrow + i][16*c + lo] = (_Float16)qacc[c][i];
        }
    }
    // NO barrier: gather below reads only this wave's own rows.

    int qv_[4], qh_[4];
    bool q0_[4];
    #pragma unroll
    for (int i = 0; i < 4; ++i) {
        const int qgl = qt0 + qrow + i;
        q0_[i] = (qgl == 0);
        int qq = qgl - 1; if (qq < 0) qq = 0;
        qv_[i] = qq / 24;
        qh_[i] = qq - qv_[i]*24;
    }

    f4 o_acc [4] = {f4{0,0,0,0}, f4{0,0,0,0}, f4{0,0,0,0}, f4{0,0,0,0}};
    f4 binacc[4] = {f4{0,0,0,0}, f4{0,0,0,0}, f4{0,0,0,0}, f4{0,0,0,0}};

    for (int kt0 = 0; kt0 < NNq; kt0 += KT) {
        h8 kb0[4], kb1[4], v0r[4], v1r[4], m20[4], m21[4];
        #pragma unroll
        for (int c = 0; c < 4; ++c) {
            const int key = kt0 + 16*c + lo;
            kb0[c] = *(const h8*)(kp + (size_t)key*HD + gb);
            kb1[c] = *(const h8*)(kp + (size_t)key*HD + 32 + gb);
            const int dd = 16*c + lo;
            v0r[c] = *(const h8*)(vp + (size_t)dd*NPAD + kt0 + gb);
            v1r[c] = *(const h8*)(vp + (size_t)dd*NPAD + kt0 + 32 + gb);
            m20[c] = *(const h8*)(M2g + (size_t)dd*NPAD + kt0 + gb);
            m21[c] = *(const h8*)(M2g + (size_t)dd*NPAD + kt0 + 32 + gb);
        }
        f4 Sc[4];
        #pragma unroll
        for (int c = 0; c < 4; ++c) {
            f4 acc = f4{0,0,0,0};
            acc = __builtin_amdgcn_mfma_f32_16x16x32_f16(a0, kb0[c], acc, 0, 0, 0);
            acc = __builtin_amdgcn_mfma_f32_16x16x32_f16(a1, kb1[c], acc, 0, 0, 0);
            Sc[c] = acc;
        }
        #pragma unroll
        for (int c = 0; c < 4; ++c) {
            const int key = kt0 + 16*c + lo;
            const bool ok = key < NNq;
            int kk = key - 1; if (kk < 0) kk = 0;
            const int kv  = kk / 24;
            const int kh2 = kk - kv*24;
            const bool kz = (key == 0);
            #pragma unroll
            for (int i = 0; i < 4; ++i) {
                int colv, colh;
                if (kz || q0_[i]) { colv = 0; colh = 30; }
                else {
                    int dv = kv  - qv_[i]; dv = min(14, max(-14, dv));
                    int dh = kh2 - qh_[i]; dh = min(14, max(-14, dh));
                    colv = dv + 15;
                    colh = 45 + dh;
                }
                const float srel = (float)qrelS[qrow+i][colv] + (float)qrelS[qrow+i][colh];
                const float p = ok ? __expf(Sc[c][i] + srel) : 0.f;
                Pt[qrow+i][16*c + lo] = (_Float16)p;
            }
        }
        const h8 p0 = *(const h8*)&Pt[16*w + lo][gb];
        const h8 p1 = *(const h8*)&Pt[16*w + lo][32 + gb];
        #pragma unroll
        for (int c = 0; c < 4; ++c) {
            binacc[c] = __builtin_amdgcn_mfma_f32_16x16x32_f16(p0, m20[c], binacc[c], 0, 0, 0);
            binacc[c] = __builtin_amdgcn_mfma_f32_16x16x32_f16(p1, m21[c], binacc[c], 0, 0, 0);
        }
        #pragma unroll
        for (int c = 0; c < 4; ++c) {
            o_acc[c] = __builtin_amdgcn_mfma_f32_16x16x32_f16(p0, v0r[c], o_acc[c], 0, 0, 0);
            o_acc[c] = __builtin_amdgcn_mfma_f32_16x16x32_f16(p1, v1r[c], o_acc[c], 0, 0, 0);
        }
    }

    __syncthreads();
    #pragma unroll
    for (int c = 0; c < 4; ++c) {
        const int bc = 16*c + lo;
        if (bc <= 50) {
            #pragma unroll
            for (int i = 0; i < 4; ++i) binsS[qrow+i][bc] = binacc[c][i];
        }
    }
    __syncthreads();

    const int b_ = bh / NHh;
    const int h_ = bh - b_*NHh;
    #pragma unroll
    for (int i = 0; i < 4; ++i) {
        const int qr  = qrow + i;
        const int qgl = qt0 + qr;
        if (qgl >= NNq) continue;
        const float l    = binsS[qr][50];
        const float invl = 1.f / l;
        float o[4] = {o_acc[0][i], o_acc[1][i], o_acc[2][i], o_acc[3][i]};
        if (qgl == 0) {
            #pragma unroll
            for (int c = 0; c < 4; ++c) {
                const int d = 16*c + lo;
                o[c] += l * (TvS[0][d] + TvS[30][d]);
            }
        } else {
            #pragma unroll
            for (int bin = 0; bin < 24; ++bin) {
                const float wq = binsS[qr][bin];
                int dv = bin - qv_[i]; dv = min(14, max(-14, dv));
                #pragma unroll
                for (int c = 0; c < 4; ++c) o[c] += wq * TvS[dv+15][16*c + lo];
            }
            {
                const float wq = binsS[qr][24];
                #pragma unroll
                for (int c = 0; c < 4; ++c) o[c] += wq * TvS[0][16*c + lo];
            }
            #pragma unroll
            for (int bin = 0; bin < 24; ++bin) {
                const float wq = binsS[qr][25+bin];
                int dh = bin - qh_[i]; dh = min(14, max(-14, dh));
                #pragma unroll
                for (int c = 0; c < 4; ++c) o[c] += wq * TvS[45+dh][16*c + lo];
            }
            {
                const float wq = binsS[qr][49];
                #pragma unroll
                for (int c = 0; c < 4; ++c) o[c] += wq * TvS[30][16*c + lo];
            }
        }
        float* dst = ao + (size_t)(b_*NNq + qgl)*DIMM + h_*HD;
        #pragma unroll
        for (int c = 0; c < 4; ++c) dst[16*c + lo] = o[c] * invl;
    }
}

// ---------------------------------------------------------------- launcher
extern "C" void kernel_launch(void* const* d_in, const int* in_sizes, int n_in,
                              void* d_out, int out_size, void* d_ws, size_t ws_size,
                              hipStream_t stream)
{
    const float* x      = (const float*)d_in[0];
    const float* qkv_w  = (const float*)d_in[1];
    const float* proj_w = (const float*)d_in[2];
    const float* proj_b = (const float*)d_in[3];
    const float* tkv    = (const float*)d_in[4];
    const float* tkh    = (const float*)d_in[5];
    const float* tvv    = (const float*)d_in[6];
    const float* tvh    = (const float*)d_in[7];
    float* out = (float*)d_out;
    float* ws  = (float*)d_ws;

    const size_t KV = (size_t)BB * NHh * NPAD * HD;      // 7,864,320 halves per tensor
    _Float16* qh  = (_Float16*)ws;
    _Float16* kh  = qh + KV;
    _Float16* vh  = kh + KV;
    float*    ao  = (float*)(vh + KV);
    _Float16* M2g = (_Float16*)(ao + (size_t)MM*DIMM);
    _Float16* xh  = M2g + NPAD*64;
    _Float16* xl  = xh + (size_t)MM*DIMM;
    _Float16* wh  = xl + (size_t)MM*DIMM;
    _Float16* wl  = wh + (size_t)NW3*DIMM;

    dim3 b256(256, 1, 1);
    // 40960 mask entries + 786432 V-pad zeros = 827392 = 3232 * 256
    mask_init<<<3232, b256, 0, stream>>>(M2g, vh);

    // (MM*DIMM + NW3*DIMM)/4 float4s = 2,214,912 = 8652 * 256
    split_pass<<<8652, b256, 0, stream>>>(x, qkv_w, xh, xl, wh, wl);

    dim3 g1(NW3/128, (MM + 127)/128, 1);                 // 18 x 73
    qkv_gemm<<<g1, b256, 0, stream>>>(xh, xl, wh, wl, qh, kh, vh);

    attn_fused<<<dim3(1920,1,1), b256, 0, stream>>>(qh, kh, vh, tkv, tkh, tvv, tvh, M2g, ao);

    dim3 g3(DIMM/128, (MM + 127)/128, 1);                // 6 x 73
    proj_gemm<<<g3, b256, 0, stream>>>(ao, proj_w, proj_b, out);
}

// Round 11
// 448.983 us; speedup vs baseline: 1.9807x; 1.1948x over previous
//
#include <hip/hip_runtime.h>

// Attention_11845519803093 — R17: pure-fp16 single-MFMA GEMMs (declared accuracy gamble).
//   Rationale: qkv output is rounded to fp16 anyway (attention runs fp16 Q/K/V/P;
//   absmax 2^-12 = fp16 half-ulp at P~1). Pure fp16 GEMM error ~1e-3 rel ≈ 2x the
//   already-accepted output rounding. If absmax fails, fallback = 2-MFMA split.
//   * convert_pass: x, qkv_w, proj_w -> fp16 once (~18MB traffic).
//   * gemm128f: single mfma per (mi,ni) per k-step (16/wave/kstep vs 48);
//     LDS 20KB -> __launch_bounds__(256,3), 3 blocks/CU.
//   * attn = R11/R16 verbatim EXCEPT epilogue stores ao as fp16 (aoh) -> proj
//     A-operand needs no conversion; attn WRITE_SIZE halves.
// ws layout: qh | kh | vh | aoh | M2 | xh | wh | pwh   (all fp16 except none)

#define BB    16
#define NNq   577
#define DIMM  768
#define NHh   12
#define HD    64
#define MM    9232
#define QT    64
#define KT    64
#define NPAD  640
#define NW3   2304

typedef _Float16 h8 __attribute__((ext_vector_type(8)));
typedef _Float16 h4 __attribute__((ext_vector_type(4)));
typedef float    f4 __attribute__((ext_vector_type(4)));

__device__ inline h8 pack8(float4 a, float4 b) {
    h8 r;
    r[0]=(_Float16)a.x; r[1]=(_Float16)a.y; r[2]=(_Float16)a.z; r[3]=(_Float16)a.w;
    r[4]=(_Float16)b.x; r[5]=(_Float16)b.y; r[6]=(_Float16)b.z; r[7]=(_Float16)b.w;
    return r;
}

// ---------------------------------------------------------------- mask table + V pad fill
__global__ void mask_init(_Float16* __restrict__ M2g, _Float16* __restrict__ vh)
{
    const int id = blockIdx.x*256 + threadIdx.x;
    if (id < NPAD*64) {
        const int key = id >> 6, bin = id & 63;
        int vb = 255, hb = 255;
        if (key == 0)      { vb = 24; hb = 49; }
        else if (key < NNq){ const int kq = key-1, kv = kq/24; vb = kv; hb = 25 + (kq - kv*24); }
        M2g[bin*NPAD + key] =
            ((key < NNq) && (bin==vb || bin==hb || bin==50)) ? (_Float16)1.f : (_Float16)0.f;
    }
    const int vid = id - NPAD*64;
    if (vid >= 0 && vid < BB*NHh*HD*64) {
        const int head = vid >> 12;
        const int rem  = vid & 4095;
        const int d    = rem >> 6;
        const int col  = 576 + (rem & 63);
        vh[(size_t)head*(HD*NPAD) + (size_t)d*NPAD + col] = (_Float16)0.f;
    }
}

// ---------------------------------------------------------------- fp32 -> fp16 convert prepass
__global__ void convert_pass(const float* __restrict__ x, const float* __restrict__ w,
                             const float* __restrict__ pw,
                             _Float16* __restrict__ xh, _Float16* __restrict__ wh,
                             _Float16* __restrict__ pwh)
{
    const size_t NX = (size_t)MM*DIMM/4;        // 1,772,544 float4s
    const size_t NW = (size_t)NW3*DIMM/4;       //   442,368
    const size_t NP = (size_t)DIMM*DIMM/4;      //   147,456
    const size_t id = (size_t)blockIdx.x*256 + threadIdx.x;
    const float4* src; h4* dst; size_t j;
    if (id < NX)            { src = (const float4*)x;  dst = (h4*)xh;  j = id; }
    else if (id < NX+NW)    { src = (const float4*)w;  dst = (h4*)wh;  j = id - NX; }
    else if (id < NX+NW+NP) { src = (const float4*)pw; dst = (h4*)pwh; j = id - NX - NW; }
    else return;
    const float4 v = src[j];
    h4 hh; hh[0]=(_Float16)v.x; hh[1]=(_Float16)v.y; hh[2]=(_Float16)v.z; hh[3]=(_Float16)v.w;
    dst[j] = hh;
}

// ---------------------------------------------------------------- pure-fp16 MFMA GEMM core
template <typename F>
__device__ __forceinline__ void gemm128f(const _Float16* __restrict__ Ah_g,
                                         const _Float16* __restrict__ Bh_g,
                                         F epi)
{
    __shared__ _Float16 Ah[128][40], Bh[128][40];
    const int t  = threadIdx.x;
    const int wv = t >> 6, lane = t & 63, lo = lane & 15, g = lane >> 4;
    const int wm = (wv >> 1) << 6, wn = (wv & 1) << 6;
    const int bm = blockIdx.y << 7, bn = blockIdx.x << 7;
    f4 acc[4][4] = {};
    const int lr = t >> 1;
    const int lc = (t & 1) << 4;
    const int am = bm + lr;
    const bool aok = am < MM;
    const _Float16* arh = Ah_g + (size_t)(aok ? am : 0) * DIMM + lc;
    const _Float16* brh = Bh_g + (size_t)(bn + lr) * DIMM + lc;

    for (int k0 = 0; k0 < DIMM; k0 += 32) {
        h8 a_h0 = {}, a_h1 = {};
        if (aok) {
            a_h0 = *(const h8*)(arh + k0); a_h1 = *(const h8*)(arh + k0 + 8);
        }
        const h8 b_h0 = *(const h8*)(brh + k0), b_h1 = *(const h8*)(brh + k0 + 8);
        __syncthreads();
        *(h8*)&Ah[lr][lc]   = a_h0;  *(h8*)&Ah[lr][lc+8] = a_h1;
        *(h8*)&Bh[lr][lc]   = b_h0;  *(h8*)&Bh[lr][lc+8] = b_h1;
        __syncthreads();
        h8 fah[4], fbh[4];
        #pragma unroll
        for (int i = 0; i < 4; ++i) {
            fah[i] = *(const h8*)&Ah[wm + 16*i + lo][g<<3];
            fbh[i] = *(const h8*)&Bh[wn + 16*i + lo][g<<3];
        }
        #pragma unroll
        for (int mi = 0; mi < 4; ++mi) {
            #pragma unroll
            for (int ni = 0; ni < 4; ++ni) {
                acc[mi][ni] = __builtin_amdgcn_mfma_f32_16x16x32_f16(fah[mi], fbh[ni], acc[mi][ni], 0, 0, 0);
            }
        }
    }
    epi(acc, bm, bn, wm, wn, lo, g);
}

// ---------------------------------------------------------------- QKV GEMM (pure fp16)
__global__ __launch_bounds__(256, 3)
void qkv_gemm(const _Float16* __restrict__ xh, const _Float16* __restrict__ wh,
              _Float16* __restrict__ qh, _Float16* __restrict__ kh, _Float16* __restrict__ vh)
{
    gemm128f(xh, wh, [=](f4 (&acc)[4][4], int bm, int bn, int wm, int wn, int lo, int g) {
        const int three = bn / 768;
        const int cb    = bn - three * 768;
        #pragma unroll
        for (int mi = 0; mi < 4; ++mi) {
            #pragma unroll
            for (int reg = 0; reg < 4; ++reg) {
                const int m = bm + wm + 16*mi + 4*g + reg;
                if (m >= MM) continue;
                const int b_ = m / NNq;
                const int n_ = m - b_ * NNq;
                #pragma unroll
                for (int ni = 0; ni < 4; ++ni) {
                    const int n  = cb + wn + 16*ni + lo;
                    const int hh = n >> 6;
                    const int d  = n & 63;
                    if (three == 0) {
                        qh[((size_t)(b_*NHh + hh)*NPAD + n_)*HD + d] = (_Float16)(acc[mi][ni][reg] * 0.125f);
                    } else if (three == 1) {
                        kh[((size_t)(b_*NHh + hh)*NPAD + n_)*HD + d] = (_Float16)acc[mi][ni][reg];
                    } else {
                        vh[((size_t)(b_*NHh + hh)*HD + d)*NPAD + n_] = (_Float16)acc[mi][ni][reg];
                    }
                }
            }
        }
    });
}

// ---------------------------------------------------------------- proj GEMM (pure fp16)
__global__ __launch_bounds__(256, 3)
void proj_gemm(const _Float16* __restrict__ aoh, const _Float16* __restrict__ pwh,
               const float* __restrict__ bias, float* __restrict__ out)
{
    gemm128f(aoh, pwh, [=](f4 (&acc)[4][4], int bm, int bn, int wm, int wn, int lo, int g) {
        #pragma unroll
        for (int ni = 0; ni < 4; ++ni) {
            const int n  = bn + wn + 16*ni + lo;
            const float bb = bias[n];
            #pragma unroll
            for (int mi = 0; mi < 4; ++mi) {
                #pragma unroll
                for (int reg = 0; reg < 4; ++reg) {
                    const int m = bm + wm + 16*mi + 4*g + reg;
                    if (m >= MM) continue;
                    out[(size_t)m*DIMM + n] = acc[mi][ni][reg] + bb;
                }
            }
        }
    });
}

// ---------------------------------------------------------------- fused attention (R11 verbatim, fp16 ao)
__global__ __launch_bounds__(256, 2)
void attn_fused(const _Float16* __restrict__ qh,
                const _Float16* __restrict__ kh, const _Float16* __restrict__ vh,
                const float* __restrict__ tkv, const float* __restrict__ tkh,
                const float* __restrict__ tvv, const float* __restrict__ tvh,
                const _Float16* __restrict__ M2g,
                _Float16* __restrict__ aoh)
{
    __shared__ __align__(16) char smem[34048];
    _Float16 (*qrelS)[72] = (_Float16(*)[72])(smem);
    _Float16 (*Pt)[72]    = (_Float16(*)[72])(smem + 9216);
    float    (*TvS)[65]   = (float(*)[65])(smem + 18432);
    float    (*binsS)[52] = (float(*)[52])(smem);

    const int t    = threadIdx.x;
    const int w    = t >> 6;
    const int lane = t & 63;
    const int lo   = lane & 15;
    const int g    = lane >> 4;
    const int gb   = g << 3;

    const int blk = blockIdx.x;            // 0..1919
    const int x8  = blk & 7;
    const int r_  = blk >> 3;              // 0..239
    const int hq  = r_ / 10;               // 0..23
    const int qt  = r_ - hq*10;            // 0..9
    const int bh  = x8 + (hq << 3);        // head 0..191
    const int qt0 = qt * QT;
    const int qrow = 16*w + 4*g;
    const _Float16* qp = qh + (size_t)bh * (NPAD*HD);
    const _Float16* kp = kh + (size_t)bh * (NPAD*HD);
    const _Float16* vp = vh + (size_t)bh * (HD*NPAD);

    for (int e = t; e < 60*64; e += 256) {
        const int r = e >> 6, d = e & 63;
        TvS[r][d] = (r < 30) ? tvv[r*HD + d] : tvh[(r-30)*HD + d];
    }

    const h8 a0 = *(const h8*)(qp + (size_t)(qt0 + 16*w + lo)*HD + gb);
    const h8 a1 = *(const h8*)(qp + (size_t)(qt0 + 16*w + lo)*HD + 32 + gb);

    {
        f4 qacc[4] = {f4{0,0,0,0}, f4{0,0,0,0}, f4{0,0,0,0}, f4{0,0,0,0}};
        #pragma unroll
        for (int c = 0; c < 4; ++c) {
            const int r16 = 16*c + lo;
            const float* src = (r16 < 30) ? (tkv + r16*HD) : (tkh + (r16-30)*HD);
            h8 tb0 = {}, tb1 = {};
            if (r16 < 60) {
                tb0 = pack8(*(const float4*)(src + gb),      *(const float4*)(src + gb + 4));
                tb1 = pack8(*(const float4*)(src + 32 + gb), *(const float4*)(src + 32 + gb + 4));
            }
            qacc[c] = __builtin_amdgcn_mfma_f32_16x16x32_f16(a0, tb0, qacc[c], 0, 0, 0);
            qacc[c] = __builtin_amdgcn_mfma_f32_16x16x32_f16(a1, tb1, qacc[c], 0, 0, 0);
        }
        #pragma unroll
        for (int c = 0; c < 4; ++c) {
            #pragma unroll
            for (int i = 0; i < 4; ++i)
                qrelS[qrow + i][16*c + lo] = (_Float16)qacc[c][i];
        }
    }
    // NO barrier: gather below reads only this wave's own rows.

    int qv_[4], qh_[4];
    bool q0_[4];
    #pragma unroll
    for (int i = 0; i < 4; ++i) {
        const int qgl = qt0 + qrow + i;
        q0_[i] = (qgl == 0);
        int qq = qgl - 1; if (qq < 0) qq = 0;
        qv_[i] = qq / 24;
        qh_[i] = qq - qv_[i]*24;
    }

    f4 o_acc [4] = {f4{0,0,0,0}, f4{0,0,0,0}, f4{0,0,0,0}, f4{0,0,0,0}};
    f4 binacc[4] = {f4{0,0,0,0}, f4{0,0,0,0}, f4{0,0,0,0}, f4{0,0,0,0}};

    for (int kt0 = 0; kt0 < NNq; kt0 += KT) {
        h8 kb0[4], kb1[4], v0r[4], v1r[4], m20[4], m21[4];
        #pragma unroll
        for (int c = 0; c < 4; ++c) {
            const int key = kt0 + 16*c + lo;
            kb0[c] = *(const h8*)(kp + (size_t)key*HD + gb);
            kb1[c] = *(const h8*)(kp + (size_t)key*HD + 32 + gb);
            const int dd = 16*c + lo;
            v0r[c] = *(const h8*)(vp + (size_t)dd*NPAD + kt0 + gb);
            v1r[c] = *(const h8*)(vp + (size_t)dd*NPAD + kt0 + 32 + gb);
            m20[c] = *(const h8*)(M2g + (size_t)dd*NPAD + kt0 + gb);
            m21[c] = *(const h8*)(M2g + (size_t)dd*NPAD + kt0 + 32 + gb);
        }
        f4 Sc[4];
        #pragma unroll
        for (int c = 0; c < 4; ++c) {
            f4 acc = f4{0,0,0,0};
            acc = __builtin_amdgcn_mfma_f32_16x16x32_f16(a0, kb0[c], acc, 0, 0, 0);
            acc = __builtin_amdgcn_mfma_f32_16x16x32_f16(a1, kb1[c], acc, 0, 0, 0);
            Sc[c] = acc;
        }
        #pragma unroll
        for (int c = 0; c < 4; ++c) {
            const int key = kt0 + 16*c + lo;
            const bool ok = key < NNq;
            int kk = key - 1; if (kk < 0) kk = 0;
            const int kv  = kk / 24;
            const int kh2 = kk - kv*24;
            const bool kz = (key == 0);
            #pragma unroll
            for (int i = 0; i < 4; ++i) {
                int colv, colh;
                if (kz || q0_[i]) { colv = 0; colh = 30; }
                else {
                    int dv = kv  - qv_[i]; dv = min(14, max(-14, dv));
                    int dh = kh2 - qh_[i]; dh = min(14, max(-14, dh));
                    colv = dv + 15;
                    colh = 45 + dh;
                }
                const float srel = (float)qrelS[qrow+i][colv] + (float)qrelS[qrow+i][colh];
                const float p = ok ? __expf(Sc[c][i] + srel) : 0.f;
                Pt[qrow+i][16*c + lo] = (_Float16)p;
            }
        }
        const h8 p0 = *(const h8*)&Pt[16*w + lo][gb];
        const h8 p1 = *(const h8*)&Pt[16*w + lo][32 + gb];
        #pragma unroll
        for (int c = 0; c < 4; ++c) {
            binacc[c] = __builtin_amdgcn_mfma_f32_16x16x32_f16(p0, m20[c], binacc[c], 0, 0, 0);
            binacc[c] = __builtin_amdgcn_mfma_f32_16x16x32_f16(p1, m21[c], binacc[c], 0, 0, 0);
        }
        #pragma unroll
        for (int c = 0; c < 4; ++c) {
            o_acc[c] = __builtin_amdgcn_mfma_f32_16x16x32_f16(p0, v0r[c], o_acc[c], 0, 0, 0);
            o_acc[c] = __builtin_amdgcn_mfma_f32_16x16x32_f16(p1, v1r[c], o_acc[c], 0, 0, 0);
        }
    }

    __syncthreads();
    #pragma unroll
    for (int c = 0; c < 4; ++c) {
        const int bc = 16*c + lo;
        if (bc <= 50) {
            #pragma unroll
            for (int i = 0; i < 4; ++i) binsS[qrow+i][bc] = binacc[c][i];
        }
    }
    __syncthreads();

    const int b_ = bh / NHh;
    const int h_ = bh - b_*NHh;
    #pragma unroll
    for (int i = 0; i < 4; ++i) {
        const int qr  = qrow + i;
        const int qgl = qt0 + qr;
        if (qgl >= NNq) continue;
        const float l    = binsS[qr][50];
        const float invl = 1.f / l;
        float o[4] = {o_acc[0][i], o_acc[1][i], o_acc[2][i], o_acc[3][i]};
        if (qgl == 0) {
            #pragma unroll
            for (int c = 0; c < 4; ++c) {
                const int d = 16*c + lo;
                o[c] += l * (TvS[0][d] + TvS[30][d]);
            }
        } else {
            #pragma unroll
            for (int bin = 0; bin < 24; ++bin) {
                const float wq = binsS[qr][bin];
                int dv = bin - qv_[i]; dv = min(14, max(-14, dv));
                #pragma unroll
                for (int c = 0; c < 4; ++c) o[c] += wq * TvS[dv+15][16*c + lo];
            }
            {
                const float wq = binsS[qr][24];
                #pragma unroll
                for (int c = 0; c < 4; ++c) o[c] += wq * TvS[0][16*c + lo];
            }
            #pragma unroll
            for (int bin = 0; bin < 24; ++bin) {
                const float wq = binsS[qr][25+bin];
                int dh = bin - qh_[i]; dh = min(14, max(-14, dh));
                #pragma unroll
                for (int c = 0; c < 4; ++c) o[c] += wq * TvS[45+dh][16*c + lo];
            }
            {
                const float wq = binsS[qr][49];
                #pragma unroll
                for (int c = 0; c < 4; ++c) o[c] += wq * TvS[30][16*c + lo];
            }
        }
        _Float16* dst = aoh + (size_t)(b_*NNq + qgl)*DIMM + h_*HD;
        #pragma unroll
        for (int c = 0; c < 4; ++c) dst[16*c + lo] = (_Float16)(o[c] * invl);
    }
}

// ---------------------------------------------------------------- launcher
extern "C" void kernel_launch(void* const* d_in, const int* in_sizes, int n_in,
                              void* d_out, int out_size, void* d_ws, size_t ws_size,
                              hipStream_t stream)
{
    const float* x      = (const float*)d_in[0];
    const float* qkv_w  = (const float*)d_in[1];
    const float* proj_w = (const float*)d_in[2];
    const float* proj_b = (const float*)d_in[3];
    const float* tkv    = (const float*)d_in[4];
    const float* tkh    = (const float*)d_in[5];
    const float* tvv    = (const float*)d_in[6];
    const float* tvh    = (const float*)d_in[7];
    float* out = (float*)d_out;
    float* ws  = (float*)d_ws;

    const size_t KV = (size_t)BB * NHh * NPAD * HD;      // 7,864,320 halves per tensor
    _Float16* qh  = (_Float16*)ws;
    _Float16* kh  = qh + KV;
    _Float16* vh  = kh + KV;
    _Float16* aoh = vh + KV;                              // MM*DIMM halves
    _Float16* M2g = aoh + (size_t)MM*DIMM;
    _Float16* xh  = M2g + NPAD*64;
    _Float16* wh  = xh + (size_t)MM*DIMM;
    _Float16* pwh = wh + (size_t)NW3*DIMM;

    dim3 b256(256, 1, 1);
    // 40960 mask entries + 786432 V-pad zeros = 827392 = 3232 * 256
    mask_init<<<3232, b256, 0, stream>>>(M2g, vh);

    // (MM + NW3 + DIMM)*DIMM/4 float4s = 2,362,368 = 9228 * 256
    convert_pass<<<9228, b256, 0, stream>>>(x, qkv_w, proj_w, xh, wh, pwh);

    dim3 g1(NW3/128, (MM + 127)/128, 1);                 // 18 x 73
    qkv_gemm<<<g1, b256, 0, stream>>>(xh, wh, qh, kh, vh);

    attn_fused<<<dim3(1920,1,1), b256, 0, stream>>>(qh, kh, vh, tkv, tkh, tvv, tvh, M2g, aoh);

    dim3 g3(DIMM/128, (MM + 127)/128, 1);                // 6 x 73
    proj_gemm<<<g3, b256, 0, stream>>>(aoh, pwh, proj_b, out);
}